// Round 4
// baseline (769.108 us; speedup 1.0000x reference)
//
#include <hip/hip_runtime.h>

// ---------------------------------------------------------------------------
// GAT 2-layer GNN on MI355X. fp32 throughout.
// Pipeline (8 dispatches):
//   memset(rcnt) -> k_bin (256-node-range counting-sort level 1)
//   -> k_sort (self-computed range base + per-range LDS counting sort)
//   -> k_gemm1 (full-K 128-row tiles; epilogue writes HEAD-MAJOR h + es/ed)
//   -> k_aggh<8> (layer-1 aggregation, per-head XCD-pinned)
//   -> k_gemm2 ([N,32]@[32,16], head-major in/out + es2/ed2 epilogue)
//   -> k_aggh<4> (layer-2 aggregation, per-head XCD-pinned)
//   -> k_final (pool + linear)
// R9 change (cache-resident gathers):
//   R8 post-mortem: deleting 77MB of roundtrips changed nothing -> the two
//   agg kernels dominate (~420us by subtraction). Cause: per-edge h-row
//   gathers (3.3M x 128B from a 12.8MB array) miss the 4MiB per-XCD L2 and
//   stream from LLC/HBM at random-access rates. Fix: HEAD-MAJOR layouts
//   h1h[4][N][8] / h2h[4][N][4]; aggregation split per head with
//   head=(blockIdx&7)>>1 so each XCD's L2 caches one 3.2MB (resp. 1.6MB)
//   head slice -> gathers become L2 hits. gemm2 un-fused (needs all heads).
// ---------------------------------------------------------------------------

#define LRELU(v) ((v) >= 0.f ? (v) : 0.2f * (v))

// Level 1: bin edges into 256-node dst ranges. Block = 8192 edges
// (256 thr x 32), two passes over the edge slice (2nd read L2-hits).
__global__ __launch_bounds__(256) void k_bin(const int* __restrict__ ei,
                                             int2* __restrict__ stg,
                                             int* __restrict__ rcnt,
                                             int E0, int Etot, int nr, int cap) {
    __shared__ int cnt[1024];
    __shared__ int base[1024];
    const int t = threadIdx.x;
    for (int i = t; i < nr; i += 256) cnt[i] = 0;
    __syncthreads();
    const int e0 = blockIdx.x * 8192;
    // pass 1: count dst ranges (dst-only load)
#pragma unroll 4
    for (int k = 0; k < 32; k++) {
        int e = e0 + k * 256 + t;
        if (e < Etot) {
            int d = (e < E0) ? ei[E0 + e] : (e - E0);
            atomicAdd(&cnt[d >> 8], 1);
        }
    }
    __syncthreads();
    // reserve per-range staging segments; reuse cnt[] as local cursor
    for (int i = t; i < nr; i += 256) {
        int c = cnt[i];
        base[i] = c ? atomicAdd(&rcnt[i], c) : 0;
        cnt[i] = 0;
    }
    __syncthreads();
    // pass 2: scatter (s,d) compactly into this block's per-range runs
#pragma unroll 4
    for (int k = 0; k < 32; k++) {
        int e = e0 + k * 256 + t;
        if (e < Etot) {
            int s, d;
            if (e < E0) {
                s = ei[e];
                d = ei[E0 + e];
            } else {
                s = d = e - E0;
            }
            int r = d >> 8;
            int slot = base[r] + atomicAdd(&cnt[r], 1);
            stg[(size_t)r * cap + slot] = make_int2(s, d);
        }
    }
}

// Level 2: one block per 256-node range. Self-computed base (reduction over
// rcnt[0..r)), LDS histogram -> exclusive scan -> row_ptr -> LDS-cursor
// scatter into the range's contiguous CSR window. No global atomics.
__global__ __launch_bounds__(512) void k_sort(const int2* __restrict__ stg,
                                              const int* __restrict__ rcnt,
                                              int* __restrict__ row_ptr,
                                              int* __restrict__ ssrc,
                                              int N, int Etot, int nr, int cap) {
    __shared__ int hist[256];
    __shared__ int hs[256];
    __shared__ int red[512];
    const int r = blockIdx.x;
    const int t = threadIdx.x;
    // rb = sum of rcnt[0..r)
    int part = 0;
    for (int i = t; i < r; i += 512) part += rcnt[i];
    red[t] = part;
    if (t < 256) hist[t] = 0;
    __syncthreads();
    for (int off = 256; off > 0; off >>= 1) {
        if (t < off) red[t] += red[t + off];
        __syncthreads();
    }
    const int rb = red[0];
    const int n0 = r << 8;
    const int cnt = rcnt[r];
    const int2* seg = stg + (size_t)r * cap;
    for (int i = t; i < cnt; i += 512) {
        int d = seg[i].y;
        atomicAdd(&hist[d - n0], 1);
    }
    __syncthreads();
    if (t < 256) hs[t] = hist[t];
    __syncthreads();
    for (int off = 1; off < 256; off <<= 1) {
        int o = (t < 256 && t >= off) ? hs[t - off] : 0;
        __syncthreads();
        if (t < 256) hs[t] += o;
        __syncthreads();
    }
    if (t < 256) {
        int excl = hs[t] - hist[t];
        int node = n0 + t;
        if (node < N) row_ptr[node] = rb + excl;
        hist[t] = excl; // reuse as running cursor
    }
    if (r == nr - 1 && t == 0) row_ptr[N] = Etot;
    __syncthreads();
    for (int i = t; i < cnt; i += 512) {
        int2 sd2 = seg[i];
        int off = atomicAdd(&hist[sd2.y - n0], 1);
        ssrc[rb + off] = sd2.x;
    }
}

// GEMM1: 128-row tiles x full K=512 (16 chunks of 32). Register prefetch.
// Epilogue writes HEAD-MAJOR: h[cg][r][8] (64B/thread contiguous) and
// es/ed[cg][r] (thread col-group cg == head, dots are thread-local).
__global__ __launch_bounds__(256) void k_gemm1(const float* __restrict__ x,
                                               const float* __restrict__ W,
                                               const float* __restrict__ a_src,
                                               const float* __restrict__ a_dst,
                                               float* __restrict__ h,
                                               float* __restrict__ es,
                                               float* __restrict__ ed, int N) {
    __shared__ float xs[32 * 132]; // [k][row], pad 132 (float2-aligned reads)
    __shared__ float ws[32 * 36];  // [k][c]
    const int t = threadIdx.x;
    const int r0 = (t >> 2) * 2; // 2 rows per thread
    const int cg = t & 3;        // 8-col group == head index
    const int row0 = blockIdx.x * 128;

    float acc[2][8];
#pragma unroll
    for (int i = 0; i < 2; i++)
#pragma unroll
        for (int j = 0; j < 8; j++) acc[i][j] = 0.f;

    float4 xr[4];
    float4 wr;
    const int xrow = t >> 3, xc4 = t & 7; // 128 rows x 8 float4/row
    const int wk = t >> 3, wc4 = t & 7;   // 32 k x 8 float4

    auto load_chunk = [&](int kc) {
#pragma unroll
        for (int ii = 0; ii < 4; ii++) {
            int row = xrow + ii * 32;
            int rr = row0 + row;
            if (rr >= N) rr = N - 1; // clamp (harmless duplicate reads)
            xr[ii] = *(const float4*)&x[(size_t)rr * 512 + kc + xc4 * 4];
        }
        wr = *(const float4*)&W[(size_t)(kc + wk) * 32 + wc4 * 4];
    };

    load_chunk(0);
    for (int c = 0; c < 16; c++) {
        __syncthreads();
#pragma unroll
        for (int ii = 0; ii < 4; ii++) {
            int row = xrow + ii * 32;
            xs[(xc4 * 4 + 0) * 132 + row] = xr[ii].x;
            xs[(xc4 * 4 + 1) * 132 + row] = xr[ii].y;
            xs[(xc4 * 4 + 2) * 132 + row] = xr[ii].z;
            xs[(xc4 * 4 + 3) * 132 + row] = xr[ii].w;
        }
        ws[wk * 36 + wc4 * 4 + 0] = wr.x;
        ws[wk * 36 + wc4 * 4 + 1] = wr.y;
        ws[wk * 36 + wc4 * 4 + 2] = wr.z;
        ws[wk * 36 + wc4 * 4 + 3] = wr.w;
        __syncthreads();
        if (c < 15) load_chunk((c + 1) * 32); // prefetch next chunk
#pragma unroll 8
        for (int k = 0; k < 32; k++) {
            float2 xv = *(const float2*)&xs[k * 132 + r0];
            float4 w0 = *(const float4*)&ws[k * 36 + cg * 8];
            float4 w1 = *(const float4*)&ws[k * 36 + cg * 8 + 4];
            acc[0][0] += xv.x * w0.x;
            acc[0][1] += xv.x * w0.y;
            acc[0][2] += xv.x * w0.z;
            acc[0][3] += xv.x * w0.w;
            acc[0][4] += xv.x * w1.x;
            acc[0][5] += xv.x * w1.y;
            acc[0][6] += xv.x * w1.z;
            acc[0][7] += xv.x * w1.w;
            acc[1][0] += xv.y * w0.x;
            acc[1][1] += xv.y * w0.y;
            acc[1][2] += xv.y * w0.z;
            acc[1][3] += xv.y * w0.w;
            acc[1][4] += xv.y * w1.x;
            acc[1][5] += xv.y * w1.y;
            acc[1][6] += xv.y * w1.z;
            acc[1][7] += xv.y * w1.w;
        }
    }

    // epilogue: head-major h rows + es/ed (head == cg)
    float4 as0 = *(const float4*)&a_src[cg * 8];
    float4 as1 = *(const float4*)&a_src[cg * 8 + 4];
    float4 ad0 = *(const float4*)&a_dst[cg * 8];
    float4 ad1 = *(const float4*)&a_dst[cg * 8 + 4];
#pragma unroll
    for (int i = 0; i < 2; i++) {
        int r = row0 + r0 + i;
        if (r < N) {
            float* hrow = h + ((size_t)cg * N + r) * 8;
            *(float4*)&hrow[0] =
                make_float4(acc[i][0], acc[i][1], acc[i][2], acc[i][3]);
            *(float4*)&hrow[4] =
                make_float4(acc[i][4], acc[i][5], acc[i][6], acc[i][7]);
            es[(size_t)cg * N + r] = acc[i][0] * as0.x + acc[i][1] * as0.y +
                                     acc[i][2] * as0.z + acc[i][3] * as0.w +
                                     acc[i][4] * as1.x + acc[i][5] * as1.y +
                                     acc[i][6] * as1.z + acc[i][7] * as1.w;
            ed[(size_t)cg * N + r] = acc[i][0] * ad0.x + acc[i][1] * ad0.y +
                                     acc[i][2] * ad0.z + acc[i][3] * ad0.w +
                                     acc[i][4] * ad1.x + acc[i][5] * ad1.y +
                                     acc[i][6] * ad1.z + acc[i][7] * ad1.w;
        }
    }
}

// Per-head aggregation, XCD-pinned. head = (blockIdx&7)>>1 so (round-robin
// block->XCD) each XCD's 4MiB L2 caches exactly one head slice of h
// (3.2MB for C=8, 1.6MB for C=4) -> per-edge row gathers become L2 hits.
// One wave per (dst,head); 4 waves/block; U-deep gather batching covers
// deg~33 in one iteration (stride U*E2 = 64).
template <int C, int U>
__global__ __launch_bounds__(256) void k_aggh(const int* __restrict__ row_ptr,
                                              const int* __restrict__ ssrc,
                                              const float* __restrict__ hbase,
                                              const float* __restrict__ esb,
                                              const float* __restrict__ edb,
                                              const float* __restrict__ bias,
                                              float* __restrict__ outb, int N) {
    constexpr int E2 = 64 / C;
    const int b = blockIdx.x;
    const int head = (b & 7) >> 1;
    const int g = (b >> 3) * 2 + (b & 1);
    const int lane = threadIdx.x & 63;
    const int d = g * 4 + (threadIdx.x >> 6);
    if (d >= N) return;
    const float* __restrict__ hh = hbase + (size_t)head * N * C;
    const float* __restrict__ esh = esb + (size_t)head * N;
    const int c = lane & (C - 1);
    const int e2 = lane / C;
    const int start = row_ptr[d];
    const int deg = row_ptr[d + 1] - start;
    const float edh = edb[(size_t)head * N + d];
    const int j0 = (e2 < deg) ? e2 : 0;

    float l = 0.f, acc = 0.f;
    for (int jb = e2; jb < deg; jb += U * E2) {
        int sv[U];
        float wv[U];
#pragma unroll
        for (int u = 0; u < U; u++) {
            int jj = jb + u * E2;
            bool ok = jj < deg;
            wv[u] = ok ? 1.f : 0.f;
            sv[u] = ssrc[start + (ok ? jj : j0)];
        }
        float hv[U];
#pragma unroll
        for (int u = 0; u < U; u++) hv[u] = hh[(size_t)sv[u] * C + c];
        float pv[U];
#pragma unroll
        for (int u = 0; u < U; u++) {
            float ev = esh[sv[u]] + edh;
            ev = LRELU(ev);
            pv[u] = __expf(ev) * wv[u];
        }
#pragma unroll
        for (int u = 0; u < U; u++) {
            l += pv[u];
            acc += pv[u] * hv[u];
        }
    }
#pragma unroll
    for (int off = C; off < 64; off <<= 1) {
        l += __shfl_xor(l, off);
        acc += __shfl_xor(acc, off);
    }
    if (lane < C) {
        float v = acc / (l + 1e-16f) + bias[head * C + c];
        outb[((size_t)head * N + d) * C + c] = v > 0.f ? v : 0.f;
    }
}

// GEMM2: head-major g1h[4][N][8] @ W2[32][16] -> h2h[4][N][4] + es2/ed2.
// 64 nodes/block; LDS-staged inputs; thread (oh = t>>6, node = t&63).
__global__ __launch_bounds__(256) void k_gemm2(const float* __restrict__ g1,
                                               const float* __restrict__ W2,
                                               const float* __restrict__ a2s,
                                               const float* __restrict__ a2d,
                                               float* __restrict__ h2,
                                               float* __restrict__ es2,
                                               float* __restrict__ ed2, int N) {
    __shared__ float rows[64 * 33];
    __shared__ float w2s[512];
    const int t = threadIdx.x;
    const int n0 = blockIdx.x * 64;
    // stage g1 (4 head slices, 512 floats each) into rows[node][hh*8+cc]
#pragma unroll
    for (int hh = 0; hh < 4; hh++) {
        int node = t >> 2, c2 = (t & 3) * 2;
        int n = n0 + node;
        if (n >= N) n = N - 1; // clamp; harmless dup (output guarded)
        float2 v = *(const float2*)&g1[((size_t)hh * N + n) * 8 + c2];
        rows[node * 33 + hh * 8 + c2] = v.x;
        rows[node * 33 + hh * 8 + c2 + 1] = v.y;
    }
    if (t < 128) {
        float4 v = *(const float4*)&W2[t * 4];
        w2s[t * 4 + 0] = v.x;
        w2s[t * 4 + 1] = v.y;
        w2s[t * 4 + 2] = v.z;
        w2s[t * 4 + 3] = v.w;
    }
    __syncthreads();
    const int oh = t >> 6, node = t & 63;
    const int n = n0 + node;
    if (n >= N) return;
    float acc[4] = {0.f, 0.f, 0.f, 0.f};
#pragma unroll 8
    for (int cc = 0; cc < 32; cc++) {
        float v = rows[node * 33 + cc];
        float4 w = *(const float4*)&w2s[cc * 16 + oh * 4];
        acc[0] += v * w.x;
        acc[1] += v * w.y;
        acc[2] += v * w.z;
        acc[3] += v * w.w;
    }
    *(float4*)&h2[((size_t)oh * N + n) * 4] =
        make_float4(acc[0], acc[1], acc[2], acc[3]);
    float s1 = 0.f, s2 = 0.f;
#pragma unroll
    for (int j = 0; j < 4; j++) {
        s1 += acc[j] * a2s[oh * 4 + j];
        s2 += acc[j] * a2d[oh * 4 + j];
    }
    es2[(size_t)oh * N + n] = s1;
    ed2[(size_t)oh * N + n] = s2;
}

// Pool (mean over sorted batch) + final linear. One block per graph.
// h3 is head-major [4][N][4]; channel ch = hh*4+c.
__global__ __launch_bounds__(256) void k_final(const float* __restrict__ h3,
                                               const int* __restrict__ batch,
                                               const float* __restrict__ Wf,
                                               const float* __restrict__ bf,
                                               float* __restrict__ out, int N) {
    __shared__ float part[16][17];
    __shared__ float pooled[16];
    int g = blockIdx.x;
    int t = threadIdx.x;

    int lo = 0, b = N;
    while (lo < b) { int mid = (lo + b) >> 1; if (batch[mid] < g) lo = mid + 1; else b = mid; }
    int hi = lo; b = N;
    while (hi < b) { int mid = (hi + b) >> 1; if (batch[mid] < g + 1) hi = mid + 1; else b = mid; }

    int ch = t & 15, r = t >> 4;
    int hh = ch >> 2, c = ch & 3;
    float acc = 0.f;
    for (int i = lo + r; i < hi; i += 16) acc += h3[((size_t)hh * N + i) * 4 + c];
    part[r][ch] = acc;
    __syncthreads();
    if (t < 16) {
        float s = 0.f;
#pragma unroll
        for (int rr = 0; rr < 16; rr++) s += part[rr][t];
        float cnt = (float)(hi - lo);
        pooled[t] = s / fmaxf(cnt, 1.f);
    }
    __syncthreads();
    if (t < 10) {
        float v = bf[t];
#pragma unroll
        for (int cc = 0; cc < 16; cc++) v += pooled[cc] * Wf[cc * 10 + t];
        out[g * 10 + t] = v;
    }
}

extern "C" void kernel_launch(void* const* d_in, const int* in_sizes, int n_in,
                              void* d_out, int out_size, void* d_ws, size_t ws_size,
                              hipStream_t stream) {
    const float* x   = (const float*)d_in[0];
    const int*   ei  = (const int*)d_in[1];
    const int*   bat = (const int*)d_in[2];
    const float* W1  = (const float*)d_in[3];
    const float* as1 = (const float*)d_in[4];
    const float* ad1 = (const float*)d_in[5];
    const float* b1  = (const float*)d_in[6];
    const float* W2  = (const float*)d_in[7];
    const float* as2 = (const float*)d_in[8];
    const float* ad2 = (const float*)d_in[9];
    const float* b2  = (const float*)d_in[10];
    const float* Wf  = (const float*)d_in[11];
    const float* bf  = (const float*)d_in[12];
    float* outp = (float*)d_out;

    const int N = in_sizes[2];
    const int E0 = in_sizes[1] / 2;
    const int Etot = E0 + N;
    const int nr = (N + 255) >> 8;    // 256-node dst ranges (<=1024)
    const int cap = Etot / nr + 2048; // per-range staging cap (~20 sigma)

    char* w = (char*)d_ws;
    auto alloc = [&](size_t bytes) -> char* {
        char* p = w;
        w += (bytes + 255) & ~(size_t)255;
        return p;
    };
    float* h1h = (float*)alloc((size_t)N * 32 * 4); // [4][N][8]
    float* es1 = (float*)alloc((size_t)N * 4 * 4);  // [4][N]
    float* ed1 = (float*)alloc((size_t)N * 4 * 4);
    float* g1h = (float*)alloc((size_t)N * 32 * 4); // [4][N][8]
    float* h2h = (float*)alloc((size_t)N * 16 * 4); // [4][N][4]
    float* es2 = (float*)alloc((size_t)N * 4 * 4);
    float* ed2 = (float*)alloc((size_t)N * 4 * 4);
    int* rcnt    = (int*)alloc(4096);
    int* row_ptr = (int*)alloc((size_t)(N + 1) * 4);
    int* ssrc    = (int*)alloc((size_t)Etot * 4);
    int2* stg    = (int2*)alloc((size_t)nr * cap * 8);
    float* h3h = h1h; // h1h dead after k_aggh<8>; reuse for layer-2 output

    const int nb1 = (N + 127) / 128;
    const int cph = (N + 7) / 8; // dst-chunks per (head,parity) lane

    hipMemsetAsync(rcnt, 0, 4096, stream);
    k_bin<<<(Etot + 8191) / 8192, 256, 0, stream>>>(ei, stg, rcnt, E0, Etot, nr, cap);
    k_sort<<<nr, 512, 0, stream>>>(stg, rcnt, row_ptr, ssrc, N, Etot, nr, cap);
    k_gemm1<<<nb1, 256, 0, stream>>>(x, W1, as1, ad1, h1h, es1, ed1, N);
    k_aggh<8, 8><<<8 * cph, 256, 0, stream>>>(row_ptr, ssrc, h1h, es1, ed1, b1, g1h, N);
    k_gemm2<<<(N + 63) / 64, 256, 0, stream>>>(g1h, W2, as2, ad2, h2h, es2, ed2, N);
    k_aggh<4, 4><<<8 * cph, 256, 0, stream>>>(row_ptr, ssrc, h2h, es2, ed2, b2, h3h, N);
    k_final<<<64, 256, 0, stream>>>(h3h, bat, Wf, bf, outp, N);
}

// Round 5
// 660.350 us; speedup vs baseline: 1.1647x; 1.1647x over previous
//
#include <hip/hip_runtime.h>

// ---------------------------------------------------------------------------
// GAT 2-layer GNN on MI355X. fp32 throughout.
// Pipeline (10 dispatches):
//   memset(rcnt) -> k_bin (256-node-range counting-sort level 1)
//   -> k_sort (range base + LDS counting sort -> row_ptr, ssrc, sdst)
//   -> k_gemm1 (full-K 128-row tiles; epilogue writes h + es/ed, node-major)
//   -> k_alpha (edge-parallel softmax numerators, zero lane redundancy)
//   -> k_agg<32> (gather-accumulate only; alpha preloaded)
//   -> k_gemm2 -> k_alpha -> k_agg<16> -> k_final
// R10 change (VALU de-redundancy):
//   R9 post-mortem: k_aggh = 173us, VALUBusy 93%, HBM 6% -> aggregation is
//   pure-VALU-bound; gathers are cache-served. The es-gather+LRELU+expf
//   chain (~15 VALU) runs 8x redundantly across channel-lanes and again on
//   predicated-off tail slots. Fix: edge-parallel k_alpha computes all 4
//   heads' exp weights once per edge (es/ed are 1.6MB = L2-resident on
//   every XCD; dst sorted -> ed reads sequential; alpha store coalesced).
//   k_agg returns to the R8 one-wave-per-dst shape, inner loop reduced to
//   {ssrc load, contiguous alpha load, h gather, 2 FMA} ~= 8-10 VALU/slot
//   (2.5x less). Numerics bit-identical to R8 (same ops, same order).
//   R9's per-head split (4x waves, 4x ssrc traffic, 50% dead slots) undone.
// ---------------------------------------------------------------------------

#define LRELU(v) ((v) >= 0.f ? (v) : 0.2f * (v))

// Level 1: bin edges into 256-node dst ranges. Block = 8192 edges
// (256 thr x 32), two passes over the edge slice (2nd read L2-hits).
__global__ __launch_bounds__(256) void k_bin(const int* __restrict__ ei,
                                             int2* __restrict__ stg,
                                             int* __restrict__ rcnt,
                                             int E0, int Etot, int nr, int cap) {
    __shared__ int cnt[1024];
    __shared__ int base[1024];
    const int t = threadIdx.x;
    for (int i = t; i < nr; i += 256) cnt[i] = 0;
    __syncthreads();
    const int e0 = blockIdx.x * 8192;
    // pass 1: count dst ranges (dst-only load)
#pragma unroll 4
    for (int k = 0; k < 32; k++) {
        int e = e0 + k * 256 + t;
        if (e < Etot) {
            int d = (e < E0) ? ei[E0 + e] : (e - E0);
            atomicAdd(&cnt[d >> 8], 1);
        }
    }
    __syncthreads();
    // reserve per-range staging segments; reuse cnt[] as local cursor
    for (int i = t; i < nr; i += 256) {
        int c = cnt[i];
        base[i] = c ? atomicAdd(&rcnt[i], c) : 0;
        cnt[i] = 0;
    }
    __syncthreads();
    // pass 2: scatter (s,d) compactly into this block's per-range runs
#pragma unroll 4
    for (int k = 0; k < 32; k++) {
        int e = e0 + k * 256 + t;
        if (e < Etot) {
            int s, d;
            if (e < E0) {
                s = ei[e];
                d = ei[E0 + e];
            } else {
                s = d = e - E0;
            }
            int r = d >> 8;
            int slot = base[r] + atomicAdd(&cnt[r], 1);
            stg[(size_t)r * cap + slot] = make_int2(s, d);
        }
    }
}

// Level 2: one block per 256-node range. Self-computed base (reduction over
// rcnt[0..r)), LDS histogram -> exclusive scan -> row_ptr -> LDS-cursor
// scatter into the range's contiguous CSR window. Emits ssrc AND sdst.
__global__ __launch_bounds__(512) void k_sort(const int2* __restrict__ stg,
                                              const int* __restrict__ rcnt,
                                              int* __restrict__ row_ptr,
                                              int* __restrict__ ssrc,
                                              int* __restrict__ sdst,
                                              int N, int Etot, int nr, int cap) {
    __shared__ int hist[256];
    __shared__ int hs[256];
    __shared__ int red[512];
    const int r = blockIdx.x;
    const int t = threadIdx.x;
    // rb = sum of rcnt[0..r)
    int part = 0;
    for (int i = t; i < r; i += 512) part += rcnt[i];
    red[t] = part;
    if (t < 256) hist[t] = 0;
    __syncthreads();
    for (int off = 256; off > 0; off >>= 1) {
        if (t < off) red[t] += red[t + off];
        __syncthreads();
    }
    const int rb = red[0];
    const int n0 = r << 8;
    const int cnt = rcnt[r];
    const int2* seg = stg + (size_t)r * cap;
    for (int i = t; i < cnt; i += 512) {
        int d = seg[i].y;
        atomicAdd(&hist[d - n0], 1);
    }
    __syncthreads();
    if (t < 256) hs[t] = hist[t];
    __syncthreads();
    for (int off = 1; off < 256; off <<= 1) {
        int o = (t < 256 && t >= off) ? hs[t - off] : 0;
        __syncthreads();
        if (t < 256) hs[t] += o;
        __syncthreads();
    }
    if (t < 256) {
        int excl = hs[t] - hist[t];
        int node = n0 + t;
        if (node < N) row_ptr[node] = rb + excl;
        hist[t] = excl; // reuse as running cursor
    }
    if (r == nr - 1 && t == 0) row_ptr[N] = Etot;
    __syncthreads();
    for (int i = t; i < cnt; i += 512) {
        int2 sd2 = seg[i];
        int off = atomicAdd(&hist[sd2.y - n0], 1);
        ssrc[rb + off] = sd2.x;
        sdst[rb + off] = sd2.y;
    }
}

// GEMM1: 128-row tiles x full K=512 (16 chunks of 32). Register prefetch.
// Epilogue: node-major h[N][32] + es/ed[N][4] (col-group cg == head).
__global__ __launch_bounds__(256) void k_gemm1(const float* __restrict__ x,
                                               const float* __restrict__ W,
                                               const float* __restrict__ a_src,
                                               const float* __restrict__ a_dst,
                                               float* __restrict__ h,
                                               float* __restrict__ es,
                                               float* __restrict__ ed, int N) {
    __shared__ float xs[32 * 132]; // [k][row], pad 132 (float2-aligned reads)
    __shared__ float ws[32 * 36];  // [k][c]
    const int t = threadIdx.x;
    const int r0 = (t >> 2) * 2; // 2 rows per thread
    const int cg = t & 3;        // 8-col group == head index
    const int row0 = blockIdx.x * 128;

    float acc[2][8];
#pragma unroll
    for (int i = 0; i < 2; i++)
#pragma unroll
        for (int j = 0; j < 8; j++) acc[i][j] = 0.f;

    float4 xr[4];
    float4 wr;
    const int xrow = t >> 3, xc4 = t & 7; // 128 rows x 8 float4/row
    const int wk = t >> 3, wc4 = t & 7;   // 32 k x 8 float4

    auto load_chunk = [&](int kc) {
#pragma unroll
        for (int ii = 0; ii < 4; ii++) {
            int row = xrow + ii * 32;
            int rr = row0 + row;
            if (rr >= N) rr = N - 1; // clamp (harmless duplicate reads)
            xr[ii] = *(const float4*)&x[(size_t)rr * 512 + kc + xc4 * 4];
        }
        wr = *(const float4*)&W[(size_t)(kc + wk) * 32 + wc4 * 4];
    };

    load_chunk(0);
    for (int c = 0; c < 16; c++) {
        __syncthreads();
#pragma unroll
        for (int ii = 0; ii < 4; ii++) {
            int row = xrow + ii * 32;
            xs[(xc4 * 4 + 0) * 132 + row] = xr[ii].x;
            xs[(xc4 * 4 + 1) * 132 + row] = xr[ii].y;
            xs[(xc4 * 4 + 2) * 132 + row] = xr[ii].z;
            xs[(xc4 * 4 + 3) * 132 + row] = xr[ii].w;
        }
        ws[wk * 36 + wc4 * 4 + 0] = wr.x;
        ws[wk * 36 + wc4 * 4 + 1] = wr.y;
        ws[wk * 36 + wc4 * 4 + 2] = wr.z;
        ws[wk * 36 + wc4 * 4 + 3] = wr.w;
        __syncthreads();
        if (c < 15) load_chunk((c + 1) * 32); // prefetch next chunk
#pragma unroll 8
        for (int k = 0; k < 32; k++) {
            float2 xv = *(const float2*)&xs[k * 132 + r0];
            float4 w0 = *(const float4*)&ws[k * 36 + cg * 8];
            float4 w1 = *(const float4*)&ws[k * 36 + cg * 8 + 4];
            acc[0][0] += xv.x * w0.x;
            acc[0][1] += xv.x * w0.y;
            acc[0][2] += xv.x * w0.z;
            acc[0][3] += xv.x * w0.w;
            acc[0][4] += xv.x * w1.x;
            acc[0][5] += xv.x * w1.y;
            acc[0][6] += xv.x * w1.z;
            acc[0][7] += xv.x * w1.w;
            acc[1][0] += xv.y * w0.x;
            acc[1][1] += xv.y * w0.y;
            acc[1][2] += xv.y * w0.z;
            acc[1][3] += xv.y * w0.w;
            acc[1][4] += xv.y * w1.x;
            acc[1][5] += xv.y * w1.y;
            acc[1][6] += xv.y * w1.z;
            acc[1][7] += xv.y * w1.w;
        }
    }

    // epilogue: h rows + es/ed (head == cg)
    float4 as0 = *(const float4*)&a_src[cg * 8];
    float4 as1 = *(const float4*)&a_src[cg * 8 + 4];
    float4 ad0 = *(const float4*)&a_dst[cg * 8];
    float4 ad1 = *(const float4*)&a_dst[cg * 8 + 4];
#pragma unroll
    for (int i = 0; i < 2; i++) {
        int r = row0 + r0 + i;
        if (r < N) {
            *(float4*)&h[(size_t)r * 32 + cg * 8] =
                make_float4(acc[i][0], acc[i][1], acc[i][2], acc[i][3]);
            *(float4*)&h[(size_t)r * 32 + cg * 8 + 4] =
                make_float4(acc[i][4], acc[i][5], acc[i][6], acc[i][7]);
            es[r * 4 + cg] = acc[i][0] * as0.x + acc[i][1] * as0.y +
                             acc[i][2] * as0.z + acc[i][3] * as0.w +
                             acc[i][4] * as1.x + acc[i][5] * as1.y +
                             acc[i][6] * as1.z + acc[i][7] * as1.w;
            ed[r * 4 + cg] = acc[i][0] * ad0.x + acc[i][1] * ad0.y +
                             acc[i][2] * ad0.z + acc[i][3] * ad0.w +
                             acc[i][4] * ad1.x + acc[i][5] * ad1.y +
                             acc[i][6] * ad1.z + acc[i][7] * ad1.w;
        }
    }
}

// Edge-parallel softmax numerators: alpha[e][h] = exp(lrelu(es[s][h]+ed[d][h])).
// One thread per edge; es/ed are 1.6MB (L2-resident on every XCD); dst is
// CSR-sorted so ed reads are sequential; alpha store fully coalesced.
__global__ __launch_bounds__(256) void k_alpha(const int* __restrict__ ssrc,
                                               const int* __restrict__ sdst,
                                               const float* __restrict__ es,
                                               const float* __restrict__ ed,
                                               float4* __restrict__ alf, int Etot) {
    int i = blockIdx.x * 256 + threadIdx.x;
    if (i >= Etot) return;
    int s = ssrc[i];
    int d = sdst[i];
    float4 a = *(const float4*)&es[(size_t)s * 4];
    float4 b = *(const float4*)&ed[(size_t)d * 4];
    float4 o;
    float v;
    v = a.x + b.x; o.x = __expf(LRELU(v));
    v = a.y + b.y; o.y = __expf(LRELU(v));
    v = a.z + b.z; o.z = __expf(LRELU(v));
    v = a.w + b.w; o.w = __expf(LRELU(v));
    alf[i] = o;
}

// Aggregation: one wave per dst, 4 dst/block, 8-deep gather batching.
// Inner loop is gather+FMA only (alpha precomputed by k_alpha).
template <int HC>
__global__ __launch_bounds__(256) void k_agg(const int* __restrict__ row_ptr,
                                             const int* __restrict__ ssrc,
                                             const float* __restrict__ hsrc,
                                             const float4* __restrict__ alf,
                                             const float* __restrict__ bias,
                                             float* __restrict__ out, int N) {
    constexpr int E2 = 64 / HC;
    constexpr int U = 8;
    const int lane = threadIdx.x & 63;
    const int d = blockIdx.x * 4 + (threadIdx.x >> 6);
    if (d >= N) return;
    const int c = lane & (HC - 1);
    const int e2 = lane / HC;
    const int hh = c / (HC / 4);
    const int start = row_ptr[d];
    const int deg = row_ptr[d + 1] - start;
    const int j0 = (e2 < deg) ? e2 : 0;

    float l = 0.f, acc = 0.f;
    for (int jb = e2; jb < deg; jb += U * E2) {
        int idx[U];
        float wv[U];
#pragma unroll
        for (int u = 0; u < U; u++) {
            int jj = jb + u * E2;
            bool ok = jj < deg;
            wv[u] = ok ? 1.f : 0.f;
            idx[u] = start + (ok ? jj : j0);
        }
        int sv[U];
#pragma unroll
        for (int u = 0; u < U; u++) sv[u] = ssrc[idx[u]];
        float av[U];
#pragma unroll
        for (int u = 0; u < U; u++)
            av[u] = ((const float*)&alf[idx[u]])[hh] * wv[u];
        float hv[U];
#pragma unroll
        for (int u = 0; u < U; u++) hv[u] = hsrc[(size_t)sv[u] * HC + c];
#pragma unroll
        for (int u = 0; u < U; u++) {
            l += av[u];
            acc += av[u] * hv[u];
        }
    }
#pragma unroll
    for (int off = HC; off < 64; off <<= 1) {
        l += __shfl_xor(l, off);
        acc += __shfl_xor(acc, off);
    }
    if (lane < HC) {
        float v = acc / (l + 1e-16f) + bias[c];
        out[(size_t)d * HC + c] = v > 0.f ? v : 0.f;
    }
}

// GEMM2: [N,32] @ [32,16] -> h2[N,16] + e_src2/e_dst2 epilogue.
__global__ __launch_bounds__(256) void k_gemm2(const float* __restrict__ g1,
                                               const float* __restrict__ W2,
                                               const float* __restrict__ a2s,
                                               const float* __restrict__ a2d,
                                               float* __restrict__ h2,
                                               float* __restrict__ es2,
                                               float* __restrict__ ed2, int N) {
    __shared__ float rows[64 * 33];
    __shared__ float ws[32 * 20];
    int t = threadIdx.x;
    int n0 = blockIdx.x * 64;
#pragma unroll
    for (int ii = 0; ii < 2; ii++) {
        int idx = ii * 256 + t;
        int node = idx >> 3, c4 = idx & 7;
        float4 v = make_float4(0.f, 0.f, 0.f, 0.f);
        if (n0 + node < N) v = *(const float4*)&g1[(size_t)(n0 + node) * 32 + c4 * 4];
        rows[node * 33 + c4 * 4 + 0] = v.x;
        rows[node * 33 + c4 * 4 + 1] = v.y;
        rows[node * 33 + c4 * 4 + 2] = v.z;
        rows[node * 33 + c4 * 4 + 3] = v.w;
    }
    if (t < 128) {
        int r = t >> 2, c4 = t & 3;
        float4 v = *(const float4*)&W2[r * 16 + c4 * 4];
        ws[r * 20 + c4 * 4 + 0] = v.x;
        ws[r * 20 + c4 * 4 + 1] = v.y;
        ws[r * 20 + c4 * 4 + 2] = v.z;
        ws[r * 20 + c4 * 4 + 3] = v.w;
    }
    __syncthreads();
    int node = t >> 2, q = t & 3;
    int n = n0 + node;
    if (n >= N) return;
    float acc[4] = {0.f, 0.f, 0.f, 0.f};
#pragma unroll 8
    for (int cc = 0; cc < 32; cc++) {
        float v = rows[node * 33 + cc];
        float4 w = *(const float4*)&ws[cc * 20 + q * 4];
        acc[0] += v * w.x;
        acc[1] += v * w.y;
        acc[2] += v * w.z;
        acc[3] += v * w.w;
    }
    *(float4*)&h2[(size_t)n * 16 + q * 4] = make_float4(acc[0], acc[1], acc[2], acc[3]);
    float s1 = 0.f, s2 = 0.f;
#pragma unroll
    for (int j = 0; j < 4; j++) {
        s1 += acc[j] * a2s[q * 4 + j];
        s2 += acc[j] * a2d[q * 4 + j];
    }
    es2[n * 4 + q] = s1;
    ed2[n * 4 + q] = s2;
}

// Pool (mean over sorted batch) + final linear. One block per graph.
__global__ __launch_bounds__(256) void k_final(const float* __restrict__ h3,
                                               const int* __restrict__ batch,
                                               const float* __restrict__ Wf,
                                               const float* __restrict__ bf,
                                               float* __restrict__ out, int N) {
    __shared__ float part[16][17];
    __shared__ float pooled[16];
    int g = blockIdx.x;
    int t = threadIdx.x;

    int lo = 0, b = N;
    while (lo < b) { int mid = (lo + b) >> 1; if (batch[mid] < g) lo = mid + 1; else b = mid; }
    int hi = lo; b = N;
    while (hi < b) { int mid = (hi + b) >> 1; if (batch[mid] < g + 1) hi = mid + 1; else b = mid; }

    int ch = t & 15, r = t >> 4;
    float acc = 0.f;
    for (int i = lo + r; i < hi; i += 16) acc += h3[(size_t)i * 16 + ch];
    part[r][ch] = acc;
    __syncthreads();
    if (t < 16) {
        float s = 0.f;
#pragma unroll
        for (int rr = 0; rr < 16; rr++) s += part[rr][t];
        float cnt = (float)(hi - lo);
        pooled[t] = s / fmaxf(cnt, 1.f);
    }
    __syncthreads();
    if (t < 10) {
        float v = bf[t];
#pragma unroll
        for (int cc = 0; cc < 16; cc++) v += pooled[cc] * Wf[cc * 10 + t];
        out[g * 10 + t] = v;
    }
}

extern "C" void kernel_launch(void* const* d_in, const int* in_sizes, int n_in,
                              void* d_out, int out_size, void* d_ws, size_t ws_size,
                              hipStream_t stream) {
    const float* x   = (const float*)d_in[0];
    const int*   ei  = (const int*)d_in[1];
    const int*   bat = (const int*)d_in[2];
    const float* W1  = (const float*)d_in[3];
    const float* as1 = (const float*)d_in[4];
    const float* ad1 = (const float*)d_in[5];
    const float* b1  = (const float*)d_in[6];
    const float* W2  = (const float*)d_in[7];
    const float* as2 = (const float*)d_in[8];
    const float* ad2 = (const float*)d_in[9];
    const float* b2  = (const float*)d_in[10];
    const float* Wf  = (const float*)d_in[11];
    const float* bf  = (const float*)d_in[12];
    float* outp = (float*)d_out;

    const int N = in_sizes[2];
    const int E0 = in_sizes[1] / 2;
    const int Etot = E0 + N;
    const int nr = (N + 255) >> 8;    // 256-node dst ranges (<=1024)
    const int cap = Etot / nr + 2048; // per-range staging cap (~20 sigma)

    char* w = (char*)d_ws;
    auto alloc = [&](size_t bytes) -> char* {
        char* p = w;
        w += (bytes + 255) & ~(size_t)255;
        return p;
    };
    float* h1  = (float*)alloc((size_t)N * 32 * 4);
    float* es1 = (float*)alloc((size_t)N * 4 * 4);
    float* ed1 = (float*)alloc((size_t)N * 4 * 4);
    float* g1  = (float*)alloc((size_t)N * 32 * 4);
    float* h2  = (float*)alloc((size_t)N * 16 * 4);
    float* es2 = (float*)alloc((size_t)N * 4 * 4);
    float* ed2 = (float*)alloc((size_t)N * 4 * 4);
    int* rcnt    = (int*)alloc(4096);
    int* row_ptr = (int*)alloc((size_t)(N + 1) * 4);
    int* ssrc    = (int*)alloc((size_t)Etot * 4);
    int* sdst    = (int*)alloc((size_t)Etot * 4);
    float4* alf  = (float4*)alloc((size_t)Etot * 16);
    int2* stg    = (int2*)alloc((size_t)nr * cap * 8);
    float* h3 = h1; // h1 dead after agg1; reuse for layer-2 output

    const int nb1 = (N + 127) / 128;
    const int nbe = (Etot + 255) / 256;

    hipMemsetAsync(rcnt, 0, 4096, stream);
    k_bin<<<(Etot + 8191) / 8192, 256, 0, stream>>>(ei, stg, rcnt, E0, Etot, nr, cap);
    k_sort<<<nr, 512, 0, stream>>>(stg, rcnt, row_ptr, ssrc, sdst, N, Etot, nr, cap);
    k_gemm1<<<nb1, 256, 0, stream>>>(x, W1, as1, ad1, h1, es1, ed1, N);
    k_alpha<<<nbe, 256, 0, stream>>>(ssrc, sdst, es1, ed1, alf, Etot);
    k_agg<32><<<(N + 3) / 4, 256, 0, stream>>>(row_ptr, ssrc, h1, alf, b1, g1, N);
    k_gemm2<<<(N + 63) / 64, 256, 0, stream>>>(g1, W2, as2, ad2, h2, es2, ed2, N);
    k_alpha<<<nbe, 256, 0, stream>>>(ssrc, sdst, es2, ed2, alf, Etot);
    k_agg<16><<<(N + 3) / 4, 256, 0, stream>>>(row_ptr, ssrc, h2, alf, b2, h3, N);
    k_final<<<64, 256, 0, stream>>>(h3, bat, Wf, bf, outp, N);
}

// Round 7
// 591.033 us; speedup vs baseline: 1.3013x; 1.1173x over previous
//
#include <hip/hip_runtime.h>

// ---------------------------------------------------------------------------
// GAT 2-layer GNN on MI355X. fp32 throughout.
// Pipeline (8 dispatches):
//   memset(rcnt) -> k_bin (256-node-range counting-sort level 1)
//   -> k_sort (range base + LDS counting sort -> row_ptr, ssrc)
//   -> k_gemm1 (full-K 128-row tiles; epilogue writes h + es/ed, node-major)
//   -> k_agg1 (float4-lane gather softmax, HC=32)
//   -> k_gemm2 ([N,32]@[32,16] + es2/ed2 epilogue)
//   -> k_agg2 (float4-lane gather softmax, HC=16) -> k_final
// R11 change (float4-lane aggregation):
//   Ledger: agg1+agg2 ~ 310us in every round R6-R10; R9 (per-head split)
//   and R10 (alpha extraction) both failed to reduce them -> the aggs are
//   bound by instructions-per-edge (one-channel-per-lane shape: ~16
//   wave-instr/edge, 64 lanes cover only 2 edges). Fix: each lane owns a
//   float4 channel quad; 8 (resp. 4) lanes fetch an edge's full h-row as
//   coalesced float4s; exp inline with only 2x (resp. 1x) redundancy;
//   U chosen so typical deg~33 completes in ONE iteration (U*E2 = 40/48).
//   ~4x fewer instructions and load-ops per edge. k_alpha/sdst deleted
//   (R10's alpha round-trip cost ~30us net, aggs saved ~0).
// R11b: resubmission — R11 bench died at container level (infra flake;
//   source audited: no OOB, no divergent barriers, ws ~85MB < R10's 150MB
//   which passed). Kernel unchanged.
// ---------------------------------------------------------------------------

#define LRELU(v) ((v) >= 0.f ? (v) : 0.2f * (v))

// Level 1: bin edges into 256-node dst ranges. Block = 8192 edges
// (256 thr x 32), two passes over the edge slice (2nd read L2-hits).
__global__ __launch_bounds__(256) void k_bin(const int* __restrict__ ei,
                                             int2* __restrict__ stg,
                                             int* __restrict__ rcnt,
                                             int E0, int Etot, int nr, int cap) {
    __shared__ int cnt[1024];
    __shared__ int base[1024];
    const int t = threadIdx.x;
    for (int i = t; i < nr; i += 256) cnt[i] = 0;
    __syncthreads();
    const int e0 = blockIdx.x * 8192;
    // pass 1: count dst ranges (dst-only load)
#pragma unroll 4
    for (int k = 0; k < 32; k++) {
        int e = e0 + k * 256 + t;
        if (e < Etot) {
            int d = (e < E0) ? ei[E0 + e] : (e - E0);
            atomicAdd(&cnt[d >> 8], 1);
        }
    }
    __syncthreads();
    // reserve per-range staging segments; reuse cnt[] as local cursor
    for (int i = t; i < nr; i += 256) {
        int c = cnt[i];
        base[i] = c ? atomicAdd(&rcnt[i], c) : 0;
        cnt[i] = 0;
    }
    __syncthreads();
    // pass 2: scatter (s,d) compactly into this block's per-range runs
#pragma unroll 4
    for (int k = 0; k < 32; k++) {
        int e = e0 + k * 256 + t;
        if (e < Etot) {
            int s, d;
            if (e < E0) {
                s = ei[e];
                d = ei[E0 + e];
            } else {
                s = d = e - E0;
            }
            int r = d >> 8;
            int slot = base[r] + atomicAdd(&cnt[r], 1);
            stg[(size_t)r * cap + slot] = make_int2(s, d);
        }
    }
}

// Level 2: one block per 256-node range. Self-computed base (reduction over
// rcnt[0..r)), LDS histogram -> exclusive scan -> row_ptr -> LDS-cursor
// scatter into the range's contiguous CSR window. No global atomics.
__global__ __launch_bounds__(512) void k_sort(const int2* __restrict__ stg,
                                              const int* __restrict__ rcnt,
                                              int* __restrict__ row_ptr,
                                              int* __restrict__ ssrc,
                                              int N, int Etot, int nr, int cap) {
    __shared__ int hist[256];
    __shared__ int hs[256];
    __shared__ int red[512];
    const int r = blockIdx.x;
    const int t = threadIdx.x;
    // rb = sum of rcnt[0..r)
    int part = 0;
    for (int i = t; i < r; i += 512) part += rcnt[i];
    red[t] = part;
    if (t < 256) hist[t] = 0;
    __syncthreads();
    for (int off = 256; off > 0; off >>= 1) {
        if (t < off) red[t] += red[t + off];
        __syncthreads();
    }
    const int rb = red[0];
    const int n0 = r << 8;
    const int cnt = rcnt[r];
    const int2* seg = stg + (size_t)r * cap;
    for (int i = t; i < cnt; i += 512) {
        int d = seg[i].y;
        atomicAdd(&hist[d - n0], 1);
    }
    __syncthreads();
    if (t < 256) hs[t] = hist[t];
    __syncthreads();
    for (int off = 1; off < 256; off <<= 1) {
        int o = (t < 256 && t >= off) ? hs[t - off] : 0;
        __syncthreads();
        if (t < 256) hs[t] += o;
        __syncthreads();
    }
    if (t < 256) {
        int excl = hs[t] - hist[t];
        int node = n0 + t;
        if (node < N) row_ptr[node] = rb + excl;
        hist[t] = excl; // reuse as running cursor
    }
    if (r == nr - 1 && t == 0) row_ptr[N] = Etot;
    __syncthreads();
    for (int i = t; i < cnt; i += 512) {
        int2 sd2 = seg[i];
        int off = atomicAdd(&hist[sd2.y - n0], 1);
        ssrc[rb + off] = sd2.x;
    }
}

// GEMM1: 128-row tiles x full K=512 (16 chunks of 32). Register prefetch.
// Epilogue: node-major h[N][32] + es/ed[N][4] (col-group cg == head).
__global__ __launch_bounds__(256) void k_gemm1(const float* __restrict__ x,
                                               const float* __restrict__ W,
                                               const float* __restrict__ a_src,
                                               const float* __restrict__ a_dst,
                                               float* __restrict__ h,
                                               float* __restrict__ es,
                                               float* __restrict__ ed, int N) {
    __shared__ float xs[32 * 132]; // [k][row], pad 132 (float2-aligned reads)
    __shared__ float ws[32 * 36];  // [k][c]
    const int t = threadIdx.x;
    const int r0 = (t >> 2) * 2; // 2 rows per thread
    const int cg = t & 3;        // 8-col group == head index
    const int row0 = blockIdx.x * 128;

    float acc[2][8];
#pragma unroll
    for (int i = 0; i < 2; i++)
#pragma unroll
        for (int j = 0; j < 8; j++) acc[i][j] = 0.f;

    float4 xr[4];
    float4 wr;
    const int xrow = t >> 3, xc4 = t & 7; // 128 rows x 8 float4/row
    const int wk = t >> 3, wc4 = t & 7;   // 32 k x 8 float4

    auto load_chunk = [&](int kc) {
#pragma unroll
        for (int ii = 0; ii < 4; ii++) {
            int row = xrow + ii * 32;
            int rr = row0 + row;
            if (rr >= N) rr = N - 1; // clamp (harmless duplicate reads)
            xr[ii] = *(const float4*)&x[(size_t)rr * 512 + kc + xc4 * 4];
        }
        wr = *(const float4*)&W[(size_t)(kc + wk) * 32 + wc4 * 4];
    };

    load_chunk(0);
    for (int c = 0; c < 16; c++) {
        __syncthreads();
#pragma unroll
        for (int ii = 0; ii < 4; ii++) {
            int row = xrow + ii * 32;
            xs[(xc4 * 4 + 0) * 132 + row] = xr[ii].x;
            xs[(xc4 * 4 + 1) * 132 + row] = xr[ii].y;
            xs[(xc4 * 4 + 2) * 132 + row] = xr[ii].z;
            xs[(xc4 * 4 + 3) * 132 + row] = xr[ii].w;
        }
        ws[wk * 36 + wc4 * 4 + 0] = wr.x;
        ws[wk * 36 + wc4 * 4 + 1] = wr.y;
        ws[wk * 36 + wc4 * 4 + 2] = wr.z;
        ws[wk * 36 + wc4 * 4 + 3] = wr.w;
        __syncthreads();
        if (c < 15) load_chunk((c + 1) * 32); // prefetch next chunk
#pragma unroll 8
        for (int k = 0; k < 32; k++) {
            float2 xv = *(const float2*)&xs[k * 132 + r0];
            float4 w0 = *(const float4*)&ws[k * 36 + cg * 8];
            float4 w1 = *(const float4*)&ws[k * 36 + cg * 8 + 4];
            acc[0][0] += xv.x * w0.x;
            acc[0][1] += xv.x * w0.y;
            acc[0][2] += xv.x * w0.z;
            acc[0][3] += xv.x * w0.w;
            acc[0][4] += xv.x * w1.x;
            acc[0][5] += xv.x * w1.y;
            acc[0][6] += xv.x * w1.z;
            acc[0][7] += xv.x * w1.w;
            acc[1][0] += xv.y * w0.x;
            acc[1][1] += xv.y * w0.y;
            acc[1][2] += xv.y * w0.z;
            acc[1][3] += xv.y * w0.w;
            acc[1][4] += xv.y * w1.x;
            acc[1][5] += xv.y * w1.y;
            acc[1][6] += xv.y * w1.z;
            acc[1][7] += xv.y * w1.w;
        }
    }

    // epilogue: h rows + es/ed (head == cg)
    float4 as0 = *(const float4*)&a_src[cg * 8];
    float4 as1 = *(const float4*)&a_src[cg * 8 + 4];
    float4 ad0 = *(const float4*)&a_dst[cg * 8];
    float4 ad1 = *(const float4*)&a_dst[cg * 8 + 4];
#pragma unroll
    for (int i = 0; i < 2; i++) {
        int r = row0 + r0 + i;
        if (r < N) {
            *(float4*)&h[(size_t)r * 32 + cg * 8] =
                make_float4(acc[i][0], acc[i][1], acc[i][2], acc[i][3]);
            *(float4*)&h[(size_t)r * 32 + cg * 8 + 4] =
                make_float4(acc[i][4], acc[i][5], acc[i][6], acc[i][7]);
            es[r * 4 + cg] = acc[i][0] * as0.x + acc[i][1] * as0.y +
                             acc[i][2] * as0.z + acc[i][3] * as0.w +
                             acc[i][4] * as1.x + acc[i][5] * as1.y +
                             acc[i][6] * as1.z + acc[i][7] * as1.w;
            ed[r * 4 + cg] = acc[i][0] * ad0.x + acc[i][1] * ad0.y +
                             acc[i][2] * ad0.z + acc[i][3] * ad0.w +
                             acc[i][4] * ad1.x + acc[i][5] * ad1.y +
                             acc[i][6] * ad1.z + acc[i][7] * ad1.w;
        }
    }
}

// Layer-1 aggregation, HC=32. One wave per dst, 4 dst/block.
// Lane = (e2 in 0..7 edge slots) x (c4 in 0..7 channel quads); each lane
// loads a float4 of h -> 8 lanes fetch an edge's full 128B row coalesced.
// head = c4>>1 (exp redundancy only 2x). U=5, stride 40: deg~33 completes
// in ONE iteration for ~90% of waves.
__global__ __launch_bounds__(256) void k_agg1(const int* __restrict__ row_ptr,
                                              const int* __restrict__ ssrc,
                                              const float* __restrict__ h,
                                              const float* __restrict__ es,
                                              const float* __restrict__ ed,
                                              const float* __restrict__ bias,
                                              float* __restrict__ out, int N) {
    constexpr int U = 5;
    const int lane = threadIdx.x & 63;
    const int d = blockIdx.x * 4 + (threadIdx.x >> 6);
    if (d >= N) return;
    const int e2 = lane >> 3; // edge slot 0..7
    const int c4 = lane & 7;  // channel quad 0..7
    const int head = c4 >> 1;
    const int start = row_ptr[d];
    const int deg = row_ptr[d + 1] - start;
    const float edh = ed[d * 4 + head];
    const int j0 = (e2 < deg) ? e2 : 0;

    float l = 0.f;
    float4 acc = make_float4(0.f, 0.f, 0.f, 0.f);
    for (int jb = e2; jb < deg; jb += U * 8) {
        int idx[U];
        float wv[U];
#pragma unroll
        for (int u = 0; u < U; u++) {
            int jj = jb + u * 8;
            bool ok = jj < deg;
            wv[u] = ok ? 1.f : 0.f;
            idx[u] = start + (ok ? jj : j0);
        }
        int sv[U];
#pragma unroll
        for (int u = 0; u < U; u++) sv[u] = ssrc[idx[u]];
        float ev[U];
#pragma unroll
        for (int u = 0; u < U; u++) ev[u] = es[sv[u] * 4 + head];
        float4 hv[U];
#pragma unroll
        for (int u = 0; u < U; u++)
            hv[u] = *(const float4*)&h[(size_t)sv[u] * 32 + c4 * 4];
#pragma unroll
        for (int u = 0; u < U; u++) {
            float e = ev[u] + edh;
            e = LRELU(e);
            float a = __expf(e) * wv[u];
            l += a;
            acc.x += a * hv[u].x;
            acc.y += a * hv[u].y;
            acc.z += a * hv[u].z;
            acc.w += a * hv[u].w;
        }
    }
#pragma unroll
    for (int off = 8; off < 64; off <<= 1) {
        l += __shfl_xor(l, off);
        acc.x += __shfl_xor(acc.x, off);
        acc.y += __shfl_xor(acc.y, off);
        acc.z += __shfl_xor(acc.z, off);
        acc.w += __shfl_xor(acc.w, off);
    }
    if (lane < 8) {
        float ls = l + 1e-16f;
        float4 b = *(const float4*)&bias[c4 * 4];
        float4 o;
        o.x = acc.x / ls + b.x;
        o.y = acc.y / ls + b.y;
        o.z = acc.z / ls + b.z;
        o.w = acc.w / ls + b.w;
        o.x = o.x > 0.f ? o.x : 0.f;
        o.y = o.y > 0.f ? o.y : 0.f;
        o.z = o.z > 0.f ? o.z : 0.f;
        o.w = o.w > 0.f ? o.w : 0.f;
        *(float4*)&out[(size_t)d * 32 + c4 * 4] = o;
    }
}

// Layer-2 aggregation, HC=16. Lane = (e2 in 0..15) x (c4 in 0..3); c4 ==
// head (no exp redundancy); float4 h2 loads (4 lanes = 64B row). U=3,
// stride 48: single iteration for ~99% of waves.
__global__ __launch_bounds__(256) void k_agg2(const int* __restrict__ row_ptr,
                                              const int* __restrict__ ssrc,
                                              const float* __restrict__ h2,
                                              const float* __restrict__ es,
                                              const float* __restrict__ ed,
                                              const float* __restrict__ bias,
                                              float* __restrict__ out, int N) {
    constexpr int U = 3;
    const int lane = threadIdx.x & 63;
    const int d = blockIdx.x * 4 + (threadIdx.x >> 6);
    if (d >= N) return;
    const int e2 = lane >> 2; // edge slot 0..15
    const int c4 = lane & 3;  // channel quad == head
    const int start = row_ptr[d];
    const int deg = row_ptr[d + 1] - start;
    const float edh = ed[d * 4 + c4];
    const int j0 = (e2 < deg) ? e2 : 0;

    float l = 0.f;
    float4 acc = make_float4(0.f, 0.f, 0.f, 0.f);
    for (int jb = e2; jb < deg; jb += U * 16) {
        int idx[U];
        float wv[U];
#pragma unroll
        for (int u = 0; u < U; u++) {
            int jj = jb + u * 16;
            bool ok = jj < deg;
            wv[u] = ok ? 1.f : 0.f;
            idx[u] = start + (ok ? jj : j0);
        }
        int sv[U];
#pragma unroll
        for (int u = 0; u < U; u++) sv[u] = ssrc[idx[u]];
        float ev[U];
#pragma unroll
        for (int u = 0; u < U; u++) ev[u] = es[sv[u] * 4 + c4];
        float4 hv[U];
#pragma unroll
        for (int u = 0; u < U; u++)
            hv[u] = *(const float4*)&h2[(size_t)sv[u] * 16 + c4 * 4];
#pragma unroll
        for (int u = 0; u < U; u++) {
            float e = ev[u] + edh;
            e = LRELU(e);
            float a = __expf(e) * wv[u];
            l += a;
            acc.x += a * hv[u].x;
            acc.y += a * hv[u].y;
            acc.z += a * hv[u].z;
            acc.w += a * hv[u].w;
        }
    }
#pragma unroll
    for (int off = 4; off < 64; off <<= 1) {
        l += __shfl_xor(l, off);
        acc.x += __shfl_xor(acc.x, off);
        acc.y += __shfl_xor(acc.y, off);
        acc.z += __shfl_xor(acc.z, off);
        acc.w += __shfl_xor(acc.w, off);
    }
    if (lane < 4) {
        float ls = l + 1e-16f;
        float4 b = *(const float4*)&bias[c4 * 4];
        float4 o;
        o.x = acc.x / ls + b.x;
        o.y = acc.y / ls + b.y;
        o.z = acc.z / ls + b.z;
        o.w = acc.w / ls + b.w;
        o.x = o.x > 0.f ? o.x : 0.f;
        o.y = o.y > 0.f ? o.y : 0.f;
        o.z = o.z > 0.f ? o.z : 0.f;
        o.w = o.w > 0.f ? o.w : 0.f;
        *(float4*)&out[(size_t)d * 16 + c4 * 4] = o;
    }
}

// GEMM2: [N,32] @ [32,16] -> h2[N,16] + e_src2/e_dst2 epilogue.
__global__ __launch_bounds__(256) void k_gemm2(const float* __restrict__ g1,
                                               const float* __restrict__ W2,
                                               const float* __restrict__ a2s,
                                               const float* __restrict__ a2d,
                                               float* __restrict__ h2,
                                               float* __restrict__ es2,
                                               float* __restrict__ ed2, int N) {
    __shared__ float rows[64 * 33];
    __shared__ float ws[32 * 20];
    int t = threadIdx.x;
    int n0 = blockIdx.x * 64;
#pragma unroll
    for (int ii = 0; ii < 2; ii++) {
        int idx = ii * 256 + t;
        int node = idx >> 3, c4 = idx & 7;
        float4 v = make_float4(0.f, 0.f, 0.f, 0.f);
        if (n0 + node < N) v = *(const float4*)&g1[(size_t)(n0 + node) * 32 + c4 * 4];
        rows[node * 33 + c4 * 4 + 0] = v.x;
        rows[node * 33 + c4 * 4 + 1] = v.y;
        rows[node * 33 + c4 * 4 + 2] = v.z;
        rows[node * 33 + c4 * 4 + 3] = v.w;
    }
    if (t < 128) {
        int r = t >> 2, c4 = t & 3;
        float4 v = *(const float4*)&W2[r * 16 + c4 * 4];
        ws[r * 20 + c4 * 4 + 0] = v.x;
        ws[r * 20 + c4 * 4 + 1] = v.y;
        ws[r * 20 + c4 * 4 + 2] = v.z;
        ws[r * 20 + c4 * 4 + 3] = v.w;
    }
    __syncthreads();
    int node = t >> 2, q = t & 3;
    int n = n0 + node;
    if (n >= N) return;
    float acc[4] = {0.f, 0.f, 0.f, 0.f};
#pragma unroll 8
    for (int cc = 0; cc < 32; cc++) {
        float v = rows[node * 33 + cc];
        float4 w = *(const float4*)&ws[cc * 20 + q * 4];
        acc[0] += v * w.x;
        acc[1] += v * w.y;
        acc[2] += v * w.z;
        acc[3] += v * w.w;
    }
    *(float4*)&h2[(size_t)n * 16 + q * 4] = make_float4(acc[0], acc[1], acc[2], acc[3]);
    float s1 = 0.f, s2 = 0.f;
#pragma unroll
    for (int j = 0; j < 4; j++) {
        s1 += acc[j] * a2s[q * 4 + j];
        s2 += acc[j] * a2d[q * 4 + j];
    }
    es2[n * 4 + q] = s1;
    ed2[n * 4 + q] = s2;
}

// Pool (mean over sorted batch) + final linear. One block per graph.
__global__ __launch_bounds__(256) void k_final(const float* __restrict__ h3,
                                               const int* __restrict__ batch,
                                               const float* __restrict__ Wf,
                                               const float* __restrict__ bf,
                                               float* __restrict__ out, int N) {
    __shared__ float part[16][17];
    __shared__ float pooled[16];
    int g = blockIdx.x;
    int t = threadIdx.x;

    int lo = 0, b = N;
    while (lo < b) { int mid = (lo + b) >> 1; if (batch[mid] < g) lo = mid + 1; else b = mid; }
    int hi = lo; b = N;
    while (hi < b) { int mid = (hi + b) >> 1; if (batch[mid] < g + 1) hi = mid + 1; else b = mid; }

    int ch = t & 15, r = t >> 4;
    float acc = 0.f;
    for (int i = lo + r; i < hi; i += 16) acc += h3[(size_t)i * 16 + ch];
    part[r][ch] = acc;
    __syncthreads();
    if (t < 16) {
        float s = 0.f;
#pragma unroll
        for (int rr = 0; rr < 16; rr++) s += part[rr][t];
        float cnt = (float)(hi - lo);
        pooled[t] = s / fmaxf(cnt, 1.f);
    }
    __syncthreads();
    if (t < 10) {
        float v = bf[t];
#pragma unroll
        for (int cc = 0; cc < 16; cc++) v += pooled[cc] * Wf[cc * 10 + t];
        out[g * 10 + t] = v;
    }
}

extern "C" void kernel_launch(void* const* d_in, const int* in_sizes, int n_in,
                              void* d_out, int out_size, void* d_ws, size_t ws_size,
                              hipStream_t stream) {
    const float* x   = (const float*)d_in[0];
    const int*   ei  = (const int*)d_in[1];
    const int*   bat = (const int*)d_in[2];
    const float* W1  = (const float*)d_in[3];
    const float* as1 = (const float*)d_in[4];
    const float* ad1 = (const float*)d_in[5];
    const float* b1  = (const float*)d_in[6];
    const float* W2  = (const float*)d_in[7];
    const float* as2 = (const float*)d_in[8];
    const float* ad2 = (const float*)d_in[9];
    const float* b2  = (const float*)d_in[10];
    const float* Wf  = (const float*)d_in[11];
    const float* bf  = (const float*)d_in[12];
    float* outp = (float*)d_out;

    const int N = in_sizes[2];
    const int E0 = in_sizes[1] / 2;
    const int Etot = E0 + N;
    const int nr = (N + 255) >> 8;    // 256-node dst ranges (<=1024)
    const int cap = Etot / nr + 2048; // per-range staging cap (~20 sigma)

    char* w = (char*)d_ws;
    auto alloc = [&](size_t bytes) -> char* {
        char* p = w;
        w += (bytes + 255) & ~(size_t)255;
        return p;
    };
    float* h1  = (float*)alloc((size_t)N * 32 * 4);
    float* es1 = (float*)alloc((size_t)N * 4 * 4);
    float* ed1 = (float*)alloc((size_t)N * 4 * 4);
    float* g1  = (float*)alloc((size_t)N * 32 * 4);
    float* h2  = (float*)alloc((size_t)N * 16 * 4);
    float* es2 = (float*)alloc((size_t)N * 4 * 4);
    float* ed2 = (float*)alloc((size_t)N * 4 * 4);
    int* rcnt    = (int*)alloc(4096);
    int* row_ptr = (int*)alloc((size_t)(N + 1) * 4);
    int* ssrc    = (int*)alloc((size_t)Etot * 4);
    int2* stg    = (int2*)alloc((size_t)nr * cap * 8);
    float* h3 = h1; // h1 dead after agg1; reuse for layer-2 output

    const int nb1 = (N + 127) / 128;

    hipMemsetAsync(rcnt, 0, 4096, stream);
    k_bin<<<(Etot + 8191) / 8192, 256, 0, stream>>>(ei, stg, rcnt, E0, Etot, nr, cap);
    k_sort<<<nr, 512, 0, stream>>>(stg, rcnt, row_ptr, ssrc, N, Etot, nr, cap);
    k_gemm1<<<nb1, 256, 0, stream>>>(x, W1, as1, ad1, h1, es1, ed1, N);
    k_agg1<<<(N + 3) / 4, 256, 0, stream>>>(row_ptr, ssrc, h1, es1, ed1, b1, g1, N);
    k_gemm2<<<(N + 63) / 64, 256, 0, stream>>>(g1, W2, as2, ad2, h2, es2, ed2, N);
    k_agg2<<<(N + 3) / 4, 256, 0, stream>>>(row_ptr, ssrc, h2, es2, ed2, b2, h3, N);
    k_final<<<64, 256, 0, stream>>>(h3, bat, Wf, bf, outp, N);
}